// Round 1
// baseline (1052.307 us; speedup 1.0000x reference)
//
#include <hip/hip_runtime.h>
#include <math.h>

// StructAttentionLayer fused kernel: B=16384, A=50, D=256, fp32.
// One block per batch row b; 256 threads = 4 waves.
// attrs[b] = 50*256 floats = 3200 float4. Thread t owns float4s at
// flat4 = i*256 + t, i=0..12 (slot 12 only for t<128).
// Row of slot i:  a = flat4>>6 = 4*i + wave  (wave-uniform!)
// Chunk of slot:  d4 = flat4&63 = lane
// => e[4i+w] = wave-reduce of per-lane dot4; attrs stay in registers and
//    are reused for the weighted output sum (single HBM pass, ~832 MiB).

#define BN 16384
#define AN 50
#define DN 256
#define ALPHA 0.2f

__global__ __launch_bounds__(256) void struct_attn_kernel(
    const float* __restrict__ attrs,
    const float* __restrict__ ent,
    const float* __restrict__ avec,
    float* __restrict__ out) {
  const int b = blockIdx.x;
  const int t = threadIdx.x;
  const int w = t >> 6;    // wave 0..3
  const int lane = t & 63;

  __shared__ float e_buf[AN];
  __shared__ float att_buf[AN];
  __shared__ float ent_buf[4];
  __shared__ __align__(16) float pbuf[4][DN];

  const float4* attrs4 = reinterpret_cast<const float4*>(attrs) + (size_t)b * (AN * DN / 4);
  const float4 aa = reinterpret_cast<const float4*>(avec)[lane];  // a_attr[4*lane..4*lane+3]

  // ---- Phase 1: load attrs into registers, per-slot dot with a_attr ----
  float4 v[13];
  float p[13];
#pragma unroll
  for (int i = 0; i < 13; ++i) {
    if (i < 12 || w < 2) {
      v[i] = attrs4[i * 256 + t];
      p[i] = v[i].x * aa.x + v[i].y * aa.y + v[i].z * aa.z + v[i].w * aa.w;
    } else {
      p[i] = 0.f;
    }
  }

  // wave-reduce each slot (all lanes end with full e[4i+w])
#pragma unroll
  for (int i = 0; i < 13; ++i) {
    float s = p[i];
    s += __shfl_xor(s, 1);
    s += __shfl_xor(s, 2);
    s += __shfl_xor(s, 4);
    s += __shfl_xor(s, 8);
    s += __shfl_xor(s, 16);
    s += __shfl_xor(s, 32);
    p[i] = s;
  }
  if (lane == 0) {
#pragma unroll
    for (int i = 0; i < 13; ++i) {
      if (i < 12 || w < 2) e_buf[4 * i + w] = p[i];
    }
  }

  // ---- entity dot: one element per thread, wave reduce, combine in LDS ----
  {
    float q = ent[(size_t)b * DN + t] * avec[DN + t];
    q += __shfl_xor(q, 1);
    q += __shfl_xor(q, 2);
    q += __shfl_xor(q, 4);
    q += __shfl_xor(q, 8);
    q += __shfl_xor(q, 16);
    q += __shfl_xor(q, 32);
    if (lane == 0) ent_buf[w] = q;
  }
  __syncthreads();

  // ---- Softmax over a (wave 0 only) ----
  if (w == 0) {
    float entd = ent_buf[0] + ent_buf[1] + ent_buf[2] + ent_buf[3];
    float el = (lane < AN) ? (e_buf[lane] + entd) : -INFINITY;
    el = (el > 0.f) ? el : ALPHA * el;  // leaky relu
    float m = el;
    m = fmaxf(m, __shfl_xor(m, 1));
    m = fmaxf(m, __shfl_xor(m, 2));
    m = fmaxf(m, __shfl_xor(m, 4));
    m = fmaxf(m, __shfl_xor(m, 8));
    m = fmaxf(m, __shfl_xor(m, 16));
    m = fmaxf(m, __shfl_xor(m, 32));
    float pe = (lane < AN) ? __expf(el - m) : 0.f;
    float s = pe;
    s += __shfl_xor(s, 1);
    s += __shfl_xor(s, 2);
    s += __shfl_xor(s, 4);
    s += __shfl_xor(s, 8);
    s += __shfl_xor(s, 16);
    s += __shfl_xor(s, 32);
    if (lane < AN) att_buf[lane] = pe * ((float)AN / s);
  }
  __syncthreads();

  // ---- Phase 2: weighted sum reusing registers ----
  float4 o = make_float4(0.f, 0.f, 0.f, 0.f);
#pragma unroll
  for (int i = 0; i < 13; ++i) {
    if (i < 12 || w < 2) {
      float at = att_buf[4 * i + w];
      o.x += at * v[i].x;
      o.y += at * v[i].y;
      o.z += at * v[i].z;
      o.w += at * v[i].w;
    }
  }
  reinterpret_cast<float4*>(&pbuf[w][0])[lane] = o;  // pbuf[w][4*lane..+3]
  __syncthreads();

  // final cross-wave combine: thread t owns output column t
  float r = pbuf[0][t] + pbuf[1][t] + pbuf[2][t] + pbuf[3][t];
  out[(size_t)b * DN + t] = r;
}

extern "C" void kernel_launch(void* const* d_in, const int* in_sizes, int n_in,
                              void* d_out, int out_size, void* d_ws, size_t ws_size,
                              hipStream_t stream) {
  const float* attrs = (const float*)d_in[0];  // (B, 50, 256) f32
  const float* ent   = (const float*)d_in[1];  // (B, 256) f32
  const float* avec  = (const float*)d_in[2];  // (512, 1) f32
  float* out = (float*)d_out;                  // (B, 256) f32
  struct_attn_kernel<<<BN, 256, 0, stream>>>(attrs, ent, avec, out);
}